// Round 6
// baseline (257.731 us; speedup 1.0000x reference)
//
#include <hip/hip_runtime.h>
#include <math.h>

#define TT 2048
#define W 10

typedef short bf16x8 __attribute__((ext_vector_type(8)));
typedef float f32x4 __attribute__((ext_vector_type(4)));

#define MFMA16(a, b, c) __builtin_amdgcn_mfma_f32_16x16x32_bf16((a), (b), (c), 0, 0, 0)

// Round-to-nearest-even hi/lo bf16 split: hi = RNE(v), r = v - hi (exact,
// Sterbenz), lo = RNE(r). |v - hi - lo| <= 2^-16 |v|, unbiased.
__device__ __forceinline__ unsigned short rneBf16(float v) {
  unsigned int u = __float_as_uint(v);
  u += 0x7FFFu + ((u >> 16) & 1u);
  return (unsigned short)(u >> 16);
}
__device__ __forceinline__ void splitRne(float v, unsigned short& hi,
                                         unsigned short& lo) {
  hi = rneBf16(v);
  float r = v - __uint_as_float((unsigned int)hi << 16);
  lo = rneBf16(r);
}

// Wt ushort layout (per array H/L), transposed [h][k] — EXACT round-3 layout:
//   W1 @0      [64][32]  : k<5   -> p1 row k
//   W2 @2048   [64][32]  : k<30  -> p2 row k
//   W3 @4096   [64][160] : k<155 -> p3 row k
//   W4 @14336  [64][512] : k<155 -> p4 row k; [155,160) zero;
//     [160,485): kap=k-160, c=kap/25, m=kap%25, j=(m+c)%25 ->
//                p4[155+m*25+j] + (c>0)*p4[155+j*25+m]   (symmetric fold)
//     [485,512) zero.
#define OFF_W2 2048
#define OFF_W3 4096
#define OFF_W4 14336
#define WT_TOTAL 47104

// ============== Kernel 1: fused [wprep | prep+gate] (R3-exact) ==============
__global__ __launch_bounds__(256) void pre_kernel(
    const float* __restrict__ F,
    const float* __restrict__ hw1, const float* __restrict__ hb1,
    const float* __restrict__ hw2, const float* __restrict__ hb2,
    const float* __restrict__ hw3, const float* __restrict__ hb3,
    const float* __restrict__ gw1, const float* __restrict__ gb1,
    const float* __restrict__ gw2, const float* __restrict__ gb2,
    const float* __restrict__ p1, const float* __restrict__ p2,
    const float* __restrict__ p3, const float* __restrict__ p4,
    unsigned short* __restrict__ WtH, unsigned short* __restrict__ WtL,
    float* __restrict__ gate) {
  const int bid = blockIdx.x;
  const int tid = threadIdx.x;
  if (bid >= 256) {
    int g = (bid - 256) * 256 + tid;
    float v;
    if (g < 2048) {
      int h = g >> 5, k = g & 31;
      v = (k < 5) ? p1[k * 64 + h] : 0.f;
    } else if (g < 4096) {
      int loc = g - 2048, h = loc >> 5, k = loc & 31;
      v = (k < 30) ? p2[k * 64 + h] : 0.f;
    } else if (g < 14336) {
      int loc = g - 4096, h = loc / 160, k = loc - h * 160;
      v = (k < 155) ? p3[k * 64 + h] : 0.f;
    } else {
      int loc = g - 14336, h = loc >> 9, k = loc & 511;
      if (k < 155) {
        v = p4[k * 64 + h];
      } else if (k >= 160 && k < 485) {
        int kap = k - 160;
        int c = kap / 25, mm = kap - c * 25;
        int jj = mm + c;
        if (jj >= 25) jj -= 25;
        v = p4[(155 + mm * 25 + jj) * 64 + h];
        if (c > 0) v += p4[(155 + jj * 25 + mm) * 64 + h];
      } else {
        v = 0.f;
      }
    }
    unsigned short hi, lo;
    splitRne(v, hi, lo);
    WtH[g] = hi;
    WtL[g] = lo;
    return;
  }
  // ---- gate block: row b, positions [t0, t0+256) ----
  __shared__ float sRet[TT];
  __shared__ float sCum[TT];
  __shared__ float sPart[256];
  const int b = bid >> 3;
  const int t0 = (bid & 7) << 8;
  const float* fb = F + (size_t)b * TT * 5;
#pragma unroll
  for (int u = 0; u < 8; ++u) {
    int t = u * 256 + tid;
    sRet[t] = (t > 0) ? (fb[t * 5] - fb[(t - 1) * 5]) : 0.f;
  }
  __syncthreads();
  float loc8[8], run = 0.f;
#pragma unroll
  for (int u = 0; u < 8; ++u) {
    run += fabsf(sRet[tid * 8 + u]);
    loc8[u] = run;
  }
  sPart[tid] = run;
  __syncthreads();
  for (int off = 1; off < 256; off <<= 1) {
    float v = (tid >= off) ? sPart[tid - off] : 0.f;
    __syncthreads();
    sPart[tid] += v;
    __syncthreads();
  }
  float excl = sPart[tid] - run;
#pragma unroll
  for (int u = 0; u < 8; ++u) sCum[tid * 8 + u] = excl + loc8[u];
  __syncthreads();
  // ---- gate MLP at t = t0 + tid ----
  const int t = t0 + tid;
  const float vv = sCum[t] / ((float)(t + 1) + 1e-8f);
  const int start = (t >= W) ? (t - W) : 0;
  float r[W];
#pragma unroll
  for (int u = 0; u < W; ++u) r[u] = sRet[start + u];
  float h1v[32];
#pragma unroll
  for (int j = 0; j < 32; ++j) {
    float a = hb1[j];
#pragma unroll
    for (int u = 0; u < W; ++u) a = fmaf(r[u], hw1[u * 32 + j], a);
    h1v[j] = fmaxf(a, 0.f);
  }
  float hs = hb3[0];
#pragma unroll
  for (int j = 0; j < 32; ++j) {
    float a = hb2[j];
#pragma unroll
    for (int u = 0; u < 32; ++u) a = fmaf(h1v[u], hw2[u * 32 + j], a);
    hs = fmaf(fmaxf(a, 0.f), hw3[j], hs);
  }
  const float H = 0.5f / (1.f + expf(-hs));
  float l0 = gb2[0], l1 = gb2[1], l2 = gb2[2], l3 = gb2[3];
#pragma unroll
  for (int j = 0; j < 32; ++j) {
    float z = fmaxf(fmaf(H, gw1[j], fmaf(vv, gw1[32 + j], gb1[j])), 0.f);
    l0 = fmaf(z, gw2[j * 4 + 0], l0);
    l1 = fmaf(z, gw2[j * 4 + 1], l1);
    l2 = fmaf(z, gw2[j * 4 + 2], l2);
    l3 = fmaf(z, gw2[j * 4 + 3], l3);
  }
  float m = fmaxf(fmaxf(l0, l1), fmaxf(l2, l3));
  float e0 = expf(l0 - m), e1 = expf(l1 - m), e2 = expf(l2 - m),
        e3 = expf(l3 - m);
  float inv = 1.f / (e0 + e1 + e2 + e3);
  ((float4*)gate)[b * TT + t] = make_float4(e0 * inv, e1 * inv, e2 * inv, e3 * inv);
}

// 5-way register select (e is loop-invariant per thread; VALU is the
// uncontended pipe — trades 2 LDS issues per row for 8 cndmask).
__device__ __forceinline__ float sel5(int e, float a, float b, float c,
                                      float d, float ee) {
  float r = (e == 0) ? a : b;
  r = (e == 2) ? c : r;
  r = (e == 3) ? d : r;
  r = (e == 4) ? ee : r;
  return r;
}

// Per-thread signature core. sRaw is PADDED [26][8] (rows 16B-aligned) so
// each row is one ds_read_b128 + one ds_read_b32 instead of 7 x b32.
// Arithmetic identical to round 3 (nE/nF now register-selected from the
// same loaded values).
template <bool GUARD>
static __device__ __forceinline__ void sigCore(const float* sR, int p, int e,
                                               int fi, float* l3a, float& aout,
                                               float& sout) {
  const float* rp = sR + (p + 10) * 8;
  f32x4 hv = *(const f32x4*)rp;
  float h0 = hv[0], h1 = hv[1], h2 = hv[2], h3 = hv[3], h4 = rp[4];
  float hiE = sel5(e, h0, h1, h2, h3, h4);
  float hiF = sel5(fi, h0, h1, h2, h3, h4);
  float a = 0.f, sfi = 0.f;
  float l0 = 0.f, l1 = 0.f, l2 = 0.f, l3 = 0.f, l4 = 0.f;
#pragma unroll
  for (int r = 9; r >= 0; --r) {
    const float* np = sR + (p + r) * 8;
    f32x4 nv = *(const f32x4*)np;
    float n0 = nv[0], n1 = nv[1], n2 = nv[2], n3 = nv[3], n4 = np[4];
    float nE = sel5(e, n0, n1, n2, n3, n4);
    float nF = sel5(fi, n0, n1, n2, n3, n4);
    float d0 = h0 - n0, d1 = h1 - n1, d2 = h2 - n2, d3 = h3 - n3, d4 = h4 - n4;
    float dE = hiE - nE, dF = hiF - nF;
    if (GUARD) {
      float vm = ((p + r) >= 10) ? 1.f : 0.f;
      d0 *= vm; d1 *= vm; d2 *= vm; d3 *= vm; d4 *= vm; dE *= vm; dF *= vm;
    }
    sfi += dF;
    float aa = a;
    l0 = fmaf(d0, aa, l0);
    l1 = fmaf(d1, aa, l1);
    l2 = fmaf(d2, aa, l2);
    l3 = fmaf(d3, aa, l3);
    l4 = fmaf(d4, aa, l4);
    a = fmaf(dE, sfi, a);
    h0 = n0; h1 = n1; h2 = n2; h3 = n3; h4 = n4; hiE = nE; hiF = nF;
  }
  l3a[0] = l0; l3a[1] = l1; l3a[2] = l2; l3a[3] = l3; l3a[4] = l4;
  aout = a;
  sout = sfi;
}

// ============== Kernel 2: phi + MFMA + head (LDS-issue optimized) ========
// phi K = 512 as round 3. Wt addressing = round 3 (flat [h][k]).
// NO LDS overlays: sXfer/sSig/sBn are dedicated buffers (46.7 KB total).
// All LDS reads in head/h2/sigCore vectorized to b128 (issue-bound fix).
// BARRIER DISCIPLINE: every __syncthreads() in block-uniform control flow.
__global__ __launch_bounds__(512, 6) void sig_kernel(
    const float* __restrict__ F, const float* __restrict__ gate,
    const unsigned short* __restrict__ WtH, const unsigned short* __restrict__ WtL,
    const float* __restrict__ p1b, const float* __restrict__ p2b,
    const float* __restrict__ p3b, const float* __restrict__ p4b,
    const float* __restrict__ w1, const float* __restrict__ b1,
    const float* __restrict__ gam, const float* __restrict__ bet,
    const float* __restrict__ rmean, const float* __restrict__ rvar,
    const float* __restrict__ w2, const float* __restrict__ b2,
    const float* __restrict__ w3, const float* __restrict__ b3,
    float* __restrict__ out) {
  __shared__ __align__(16) unsigned short phiH[16][520];
  __shared__ __align__(16) unsigned short phiL[16][520];
  __shared__ __align__(16) float sRaw[26 * 8];   // padded rows
  __shared__ __align__(16) float sXfer[4 * 64 * 4];
  __shared__ __align__(16) float sSig[16 * 68];
  __shared__ __align__(16) float sBn[16 * 64];

  const int tid = threadIdx.x;
  const int posBase = blockIdx.x * 16;
  const int t0 = posBase & (TT - 1);

  // ---- P0: zero phi pads + stage F window (26 rows x 8 padded) ----
  {
    int p = tid >> 5, mm = tid & 31;
    int kk = (mm < 5) ? (155 + mm) : (480 + mm);  // [155,160) and [485,512)
    phiH[p][kk] = 0;
    phiL[p][kk] = 0;
  }
  if (tid < 208) {
    int lr = tid >> 3, cc = tid & 7;
    int tq = t0 - W + lr;
    float v = 0.f;
    if (cc < 5 && tq >= 0) v = F[(size_t)(posBase - t0) * 5 + tq * 5 + cc];
    sRaw[tid] = v;
  }
  __syncthreads();

  // ---- P1: fused l1/l2/l3 (register revcumsum) + l4 (in-wave shuffle) ----
  const int pgrp = tid >> 5;  // position group, half-wave aligned
  const int m = tid & 31;     // 25 active lanes per group
  float l2v = 0.f;
  if (m < 25) {
    const int e = m / 5;
    const int fi = m - e * 5;
    float l3a[5], a, sfi;
    if (t0 != 0)
      sigCore<false>(sRaw, pgrp, e, fi, l3a, a, sfi);
    else
      sigCore<true>(sRaw, pgrp, e, fi, l3a, a, sfi);
    l2v = a;
    unsigned short hi, lo;
    if (m < 5) {
      splitRne(sfi, hi, lo);  // lvl1 = S[0, m]
      phiH[pgrp][m] = hi;
      phiL[pgrp][m] = lo;
    }
    splitRne(a, hi, lo);  // l2f[m]
    phiH[pgrp][5 + m] = hi;
    phiL[pgrp][5 + m] = lo;
#pragma unroll
    for (int i = 0; i < 5; ++i) {  // l3f[i*25+m]
      splitRne(l3a[i], hi, lo);
      phiH[pgrp][30 + i * 25 + m] = hi;
      phiL[pgrp][30 + i * 25 + m] = lo;
    }
  }
  // l4 symmetric products: pair {m, (m+c)%25}, c=0..12 -> phi k = 160+c*25+m
  const int laneBase = tid & 32;
#pragma unroll
  for (int c = 0; c < 13; ++c) {
    int j = m + c;
    if (j >= 25) j -= 25;
    float other = __shfl(l2v, laneBase + j, 64);
    if (m < 25) {
      unsigned short hi, lo;
      splitRne(l2v * other, hi, lo);
      phiH[pgrp][160 + c * 25 + m] = hi;
      phiL[pgrp][160 + c * 25 + m] = lo;
    }
  }
  __syncthreads();

  // ---- P2: MFMA. wave = (h-tile ht, K-group kg). R3 Wt addressing. ----
  const int lane = tid & 63;
  const int wv = tid >> 6;  // 0..7
  const int ht = wv & 3, kg = wv >> 2;
  const int col = lane & 15, quad = lane >> 4;
  const int hw = ht * 16;
  const int arow = hw + col;

  const unsigned short* bHp = &phiH[col][quad * 8];
  const unsigned short* bLp = &phiL[col][quad * 8];
  const unsigned short* a4H = WtH + OFF_W4 + arow * 512 + quad * 8;
  const unsigned short* a4L = WtL + OFF_W4 + arow * 512 + quad * 8;

  const int pos = posBase + col;
  const int t = pos & (TT - 1);
  float4 g = ((const float4*)gate)[pos];
  const float g0 = g.x;
  const float g1 = (t >= 1) ? g.y : 0.f;
  const float g2 = (t >= 2) ? g.z : 0.f;
  const float g3 = (t >= 3) ? g.w : 0.f;

  f32x4 res;      // kg0: g3*a4 + gated bias;  kg1: gate-combined partials
  if (kg == 0) {  // W4 slices 0..11: 36 MFMAs
    f32x4 t4a = {0.f, 0.f, 0.f, 0.f}, t4b = {0.f, 0.f, 0.f, 0.f};
    for (int s = 0; s < 12; ++s) {
      bf16x8 bh = *(const bf16x8*)(bHp + s * 32);
      bf16x8 bl = *(const bf16x8*)(bLp + s * 32);
      bf16x8 ah = *(const bf16x8*)(a4H + s * 32);
      bf16x8 al = *(const bf16x8*)(a4L + s * 32);
      t4a = MFMA16(ah, bh, t4a);
      t4b = MFMA16(ah, bl, t4b);
      t4b = MFMA16(al, bh, t4b);
    }
    f32x4 a4 = t4a + t4b;
    const int hq = hw + quad * 4;
    f32x4 b1v = *(const f32x4*)(p1b + hq);
    f32x4 b2v = *(const f32x4*)(p2b + hq);
    f32x4 b3v = *(const f32x4*)(p3b + hq);
    f32x4 b4v = *(const f32x4*)(p4b + hq);
#pragma unroll
    for (int r = 0; r < 4; ++r)
      res[r] = g3 * a4[r] + g0 * b1v[r] + g1 * b2v[r] + g2 * b3v[r] + g3 * b4v[r];
  } else {  // W4 slices 12..15 + W3 + W2 + W1: 33 MFMAs
    f32x4 t4a = {0.f, 0.f, 0.f, 0.f}, t4b = {0.f, 0.f, 0.f, 0.f};
    for (int s = 12; s < 16; ++s) {
      bf16x8 bh = *(const bf16x8*)(bHp + s * 32);
      bf16x8 bl = *(const bf16x8*)(bLp + s * 32);
      bf16x8 ah = *(const bf16x8*)(a4H + s * 32);
      bf16x8 al = *(const bf16x8*)(a4L + s * 32);
      t4a = MFMA16(ah, bh, t4a);
      t4b = MFMA16(ah, bl, t4b);
      t4b = MFMA16(al, bh, t4b);
    }
    f32x4 a4 = t4a + t4b;
    const unsigned short* a3H = WtH + OFF_W3 + arow * 160 + quad * 8;
    const unsigned short* a3L = WtL + OFF_W3 + arow * 160 + quad * 8;
    f32x4 t3a = {0.f, 0.f, 0.f, 0.f}, t3b = {0.f, 0.f, 0.f, 0.f};
    for (int s = 0; s < 5; ++s) {
      bf16x8 bh = *(const bf16x8*)(bHp + s * 32);
      bf16x8 bl = *(const bf16x8*)(bLp + s * 32);
      bf16x8 ch = *(const bf16x8*)(a3H + s * 32);
      bf16x8 cl = *(const bf16x8*)(a3L + s * 32);
      t3a = MFMA16(ch, bh, t3a);
      t3b = MFMA16(ch, bl, t3b);
      t3b = MFMA16(cl, bh, t3b);
    }
    f32x4 a3 = t3a + t3b;
    bf16x8 bh0 = *(const bf16x8*)(bHp);
    bf16x8 bl0 = *(const bf16x8*)(bLp);
    f32x4 acc2 = {0.f, 0.f, 0.f, 0.f}, acc1 = {0.f, 0.f, 0.f, 0.f};
    const unsigned short* a2H = WtH + OFF_W2 + arow * 32 + quad * 8;
    const unsigned short* a2L = WtL + OFF_W2 + arow * 32 + quad * 8;
    bf16x8 dh = *(const bf16x8*)a2H;
    bf16x8 dl = *(const bf16x8*)a2L;
    acc2 = MFMA16(dh, bh0, acc2);
    acc2 = MFMA16(dh, bl0, acc2);
    acc2 = MFMA16(dl, bh0, acc2);
    const unsigned short* a1H = WtH + arow * 32 + quad * 8;
    const unsigned short* a1L = WtL + arow * 32 + quad * 8;
    bf16x8 eh = *(const bf16x8*)a1H;
    bf16x8 el = *(const bf16x8*)a1L;
    acc1 = MFMA16(eh, bh0, acc1);
    acc1 = MFMA16(eh, bl0, acc1);
    acc1 = MFMA16(el, bh0, acc1);
#pragma unroll
    for (int r = 0; r < 4; ++r)
      res[r] = g0 * acc1[r] + g1 * acc2[r] + g2 * a3[r] + g3 * a4[r];
  }

  // ---- fold kg1 -> kg0 through dedicated sXfer; single sSig stream ----
  if (kg == 1) *(f32x4*)&sXfer[(ht * 64 + lane) * 4] = res;
  __syncthreads();  // UNIFORM
  if (kg == 0) {
    f32x4 xf = *(const f32x4*)&sXfer[(ht * 64 + lane) * 4];
    f32x4 fin = res + xf;
    *(f32x4*)&sSig[col * 68 + hw + quad * 4] = fin;
  }
  __syncthreads();  // UNIFORM

  // ---- Head: h1+BN. wave handles 2 positions, lane = output channel j ----
  // sSig reads are wave-uniform b128 broadcasts (16 per position).
  {
    const int j = lane;
    const int pA = wv * 2, pB = pA + 1;
    float a0 = b1[j], a1 = a0;
    const float* srow0 = sSig + pA * 68;
    const float* srow1 = sSig + pB * 68;
    for (int i4 = 0; i4 < 16; ++i4) {
      f32x4 s0 = *(const f32x4*)(srow0 + i4 * 4);
      f32x4 s1 = *(const f32x4*)(srow1 + i4 * 4);
#pragma unroll
      for (int r = 0; r < 4; ++r) {
        float wt = w1[(i4 * 4 + r) * 64 + j];
        a0 = fmaf(s0[r], wt, a0);
        a1 = fmaf(s1[r], wt, a1);
      }
    }
    const float* fp0 = sRaw + (10 + pA) * 8;
    const float* fp1 = sRaw + (10 + pB) * 8;
    f32x4 fa = *(const f32x4*)fp0;
    float fa4 = fp0[4];
    f32x4 fbv = *(const f32x4*)fp1;
    float fb4 = fp1[4];
#pragma unroll
    for (int i = 0; i < 4; ++i) {
      float wt = w1[(64 + i) * 64 + j];
      a0 = fmaf(fa[i], wt, a0);
      a1 = fmaf(fbv[i], wt, a1);
    }
    {
      float wt4 = w1[68 * 64 + j];
      a0 = fmaf(fa4, wt4, a0);
      a1 = fmaf(fb4, wt4, a1);
    }
    float sc = gam[j] * rsqrtf(rvar[j] + 1e-5f);
    float rm = rmean[j], be = bet[j];
    sBn[pA * 64 + j] = fmaf(fmaxf(a0, 0.f) - rm, sc, be);
    sBn[pB * 64 + j] = fmaf(fmaxf(a1, 0.f) - rm, sc, be);
  }
  __syncthreads();  // UNIFORM

  // ---- h2 + output: 512 tasks = 16 pos x 32 k; b128 bn reads ----
  {
    const float b3s = b3[0];
    int p = tid >> 5, k = tid & 31;
    const float* bnp = sBn + p * 64;
    float a = b2[k];
    for (int j4 = 0; j4 < 16; ++j4) {
      f32x4 bv = *(const f32x4*)(bnp + j4 * 4);
#pragma unroll
      for (int r = 0; r < 4; ++r) a = fmaf(bv[r], w2[(j4 * 4 + r) * 32 + k], a);
    }
    float partial = fmaxf(a, 0.f) * w3[k];
#pragma unroll
    for (int off = 16; off >= 1; off >>= 1) partial += __shfl_xor(partial, off, 32);
    if (k == 0) out[posBase + p] = 1.5f * tanhf(partial + b3s);
  }
}

extern "C" void kernel_launch(void* const* d_in, const int* in_sizes, int n_in,
                              void* d_out, int out_size, void* d_ws, size_t ws_size,
                              hipStream_t stream) {
  const float* F = (const float*)d_in[0];
  const float* hw1 = (const float*)d_in[1];
  const float* hb1 = (const float*)d_in[2];
  const float* hw2 = (const float*)d_in[3];
  const float* hb2 = (const float*)d_in[4];
  const float* hw3 = (const float*)d_in[5];
  const float* hb3 = (const float*)d_in[6];
  const float* gw1 = (const float*)d_in[7];
  const float* gb1 = (const float*)d_in[8];
  const float* gw2 = (const float*)d_in[9];
  const float* gb2 = (const float*)d_in[10];
  const float* p1 = (const float*)d_in[11];
  const float* p1b = (const float*)d_in[12];
  const float* p2 = (const float*)d_in[13];
  const float* p2b = (const float*)d_in[14];
  const float* p3 = (const float*)d_in[15];
  const float* p3b = (const float*)d_in[16];
  const float* p4 = (const float*)d_in[17];
  const float* p4b = (const float*)d_in[18];
  const float* w1 = (const float*)d_in[19];
  const float* b1 = (const float*)d_in[20];
  const float* gam = (const float*)d_in[21];
  const float* bet = (const float*)d_in[22];
  const float* rmean = (const float*)d_in[23];
  const float* rvar = (const float*)d_in[24];
  const float* w2 = (const float*)d_in[25];
  const float* b2 = (const float*)d_in[26];
  const float* w3 = (const float*)d_in[27];
  const float* b3 = (const float*)d_in[28];

  float* ws = (float*)d_ws;
  float* gate = ws;                                      // 262144 floats
  unsigned short* WtH = (unsigned short*)(ws + 262144);  // 47104 ushorts
  unsigned short* WtL = WtH + WT_TOTAL;                  // 47104 ushorts
  float* out = (float*)d_out;                            // 65536 floats

  // 256 gate blocks + 184 repack blocks (47104 / 256)
  pre_kernel<<<440, 256, 0, stream>>>(F, hw1, hb1, hw2, hb2, hw3, hb3, gw1,
                                      gb1, gw2, gb2, p1, p2, p3, p4, WtH, WtL,
                                      gate);
  sig_kernel<<<4096, 512, 0, stream>>>(F, gate, WtH, WtL, p1b, p2b, p3b, p4b,
                                       w1, b1, gam, bet, rmean, rvar, w2, b2,
                                       w3, b3, out);
}

// Round 8
// 241.059 us; speedup vs baseline: 1.0692x; 1.0692x over previous
//
#include <hip/hip_runtime.h>
#include <math.h>

#define TT 2048
#define W 10

typedef short bf16x8 __attribute__((ext_vector_type(8)));
typedef float f32x4 __attribute__((ext_vector_type(4)));

// Truncation-based hi/lo bf16 split: hi = trunc(v), lo = trunc(v - hi).
// v - hi is exact in fp32; residual after hi+lo <= 2^-16 |v|. lo catches the
// truncation error, so rounding hi would buy nothing. ~4 VALU vs ~10 for RNE.
__device__ __forceinline__ void splitTrunc(float v, unsigned short& hi,
                                           unsigned short& lo) {
  unsigned int u = __float_as_uint(v);
  hi = (unsigned short)(u >> 16);
  float r = v - __uint_as_float(u & 0xffff0000u);
  lo = (unsigned short)(__float_as_uint(r) >> 16);
}

// ============== Kernel 1: fused [wprep | prep+gate] ==============
// blocks [0,256): gate for one (row, 256-pos chunk); redundant per-block scan.
// blocks [256,512): weight repack to bf16 hi/lo, transposed [h][k], K padded.
// Wt layout (ushort): W1 @0 (64x32), W2 @2048 (64x32), W3 @4096 (64x160),
// W4 @14336 (64x800) with phi-k mapping: k<155 -> p4 row k; [155,160) zero;
// [160,785) -> p4 row k-5; [785,800) zero.  (l4f lives at phi k=160 so that
// phase-1c writes are even-aligned for packed b32 LDS stores.)
__global__ __launch_bounds__(256) void pre_kernel(
    const float* __restrict__ F,
    const float* __restrict__ hw1, const float* __restrict__ hb1,
    const float* __restrict__ hw2, const float* __restrict__ hb2,
    const float* __restrict__ hw3, const float* __restrict__ hb3,
    const float* __restrict__ gw1, const float* __restrict__ gb1,
    const float* __restrict__ gw2, const float* __restrict__ gb2,
    const float* __restrict__ p1, const float* __restrict__ p2,
    const float* __restrict__ p3, const float* __restrict__ p4,
    unsigned short* __restrict__ WtH, unsigned short* __restrict__ WtL,
    float* __restrict__ gate) {
  const int bid = blockIdx.x;
  const int tid = threadIdx.x;
  if (bid >= 256) {
    int g = (bid - 256) * 256 + tid;
    float v;
    if (g < 2048) {
      int h = g >> 5, k = g & 31;
      v = (k < 5) ? p1[k * 64 + h] : 0.f;
    } else if (g < 4096) {
      int loc = g - 2048, h = loc >> 5, k = loc & 31;
      v = (k < 30) ? p2[k * 64 + h] : 0.f;
    } else if (g < 14336) {
      int loc = g - 4096, h = loc / 160, k = loc - h * 160;
      v = (k < 155) ? p3[k * 64 + h] : 0.f;
    } else {
      int loc = g - 14336, h = loc / 800, k = loc - h * 800;
      if (k < 155) v = p4[k * 64 + h];
      else if (k >= 160 && k < 785) v = p4[(k - 5) * 64 + h];
      else v = 0.f;
    }
    unsigned short hi, lo;
    splitTrunc(v, hi, lo);
    WtH[g] = hi;
    WtL[g] = lo;
    return;
  }
  // ---- gate block: row b, positions [t0, t0+256) ----
  __shared__ float sRet[TT];
  __shared__ float sCum[TT];
  __shared__ float sPart[256];
  const int b = bid >> 3;
  const int t0 = (bid & 7) << 8;
  const float* fb = F + (size_t)b * TT * 5;
#pragma unroll
  for (int u = 0; u < 8; ++u) {
    int t = u * 256 + tid;
    sRet[t] = (t > 0) ? (fb[t * 5] - fb[(t - 1) * 5]) : 0.f;
  }
  __syncthreads();
  float loc8[8], run = 0.f;
#pragma unroll
  for (int u = 0; u < 8; ++u) {
    run += fabsf(sRet[tid * 8 + u]);
    loc8[u] = run;
  }
  sPart[tid] = run;
  __syncthreads();
  for (int off = 1; off < 256; off <<= 1) {
    float v = (tid >= off) ? sPart[tid - off] : 0.f;
    __syncthreads();
    sPart[tid] += v;
    __syncthreads();
  }
  float excl = sPart[tid] - run;
#pragma unroll
  for (int u = 0; u < 8; ++u) sCum[tid * 8 + u] = excl + loc8[u];
  __syncthreads();
  // ---- gate MLP at t = t0 + tid ----
  const int t = t0 + tid;
  const float vv = sCum[t] / ((float)(t + 1) + 1e-8f);
  const int start = (t >= W) ? (t - W) : 0;
  float r[W];
#pragma unroll
  for (int u = 0; u < W; ++u) r[u] = sRet[start + u];
  float h1v[32];
#pragma unroll
  for (int j = 0; j < 32; ++j) {
    float a = hb1[j];
#pragma unroll
    for (int u = 0; u < W; ++u) a = fmaf(r[u], hw1[u * 32 + j], a);
    h1v[j] = fmaxf(a, 0.f);
  }
  float hs = hb3[0];
#pragma unroll
  for (int j = 0; j < 32; ++j) {
    float a = hb2[j];
#pragma unroll
    for (int u = 0; u < 32; ++u) a = fmaf(h1v[u], hw2[u * 32 + j], a);
    hs = fmaf(fmaxf(a, 0.f), hw3[j], hs);
  }
  const float H = 0.5f / (1.f + expf(-hs));
  float l0 = gb2[0], l1 = gb2[1], l2 = gb2[2], l3 = gb2[3];
#pragma unroll
  for (int j = 0; j < 32; ++j) {
    float z = fmaxf(fmaf(H, gw1[j], fmaf(vv, gw1[32 + j], gb1[j])), 0.f);
    l0 = fmaf(z, gw2[j * 4 + 0], l0);
    l1 = fmaf(z, gw2[j * 4 + 1], l1);
    l2 = fmaf(z, gw2[j * 4 + 2], l2);
    l3 = fmaf(z, gw2[j * 4 + 3], l3);
  }
  float m = fmaxf(fmaxf(l0, l1), fmaxf(l2, l3));
  float e0 = expf(l0 - m), e1 = expf(l1 - m), e2 = expf(l2 - m),
        e3 = expf(l3 - m);
  float inv = 1.f / (e0 + e1 + e2 + e3);
  ((float4*)gate)[b * TT + t] = make_float4(e0 * inv, e1 * inv, e2 * inv, e3 * inv);
}

// ============== Kernel 2: signature phi (bf16 hi/lo) + MFMA + head ==============
// 512 threads = 8 waves = 4 h-tiles x 2 K-groups (48 MFMAs each).
// Gate-combine is linear => each K-group folds its partial projections with
// the gate immediately; only one f32x4/lane crosses LDS for the reduction.
#define MFMA16(a, b, c) __builtin_amdgcn_mfma_f32_16x16x32_bf16((a), (b), (c), 0, 0, 0)

__global__ __launch_bounds__(512, 4) void sig_kernel(
    const float* __restrict__ F, const float* __restrict__ gate,
    const unsigned short* __restrict__ WtH, const unsigned short* __restrict__ WtL,
    const float* __restrict__ p1b, const float* __restrict__ p2b,
    const float* __restrict__ p3b, const float* __restrict__ p4b,
    const float* __restrict__ w1, const float* __restrict__ b1,
    const float* __restrict__ gam, const float* __restrict__ bet,
    const float* __restrict__ rmean, const float* __restrict__ rvar,
    const float* __restrict__ w2, const float* __restrict__ b2,
    const float* __restrict__ w3, const float* __restrict__ b3,
    float* __restrict__ out) {
  // phi rows: 808-ushort stride (1616 B): 16B-aligned rows, 2-way-max bank
  // aliasing on b128 fragment reads (free per m136).
  __shared__ unsigned short phiH[16][808];
  __shared__ unsigned short phiL[16][808];
  // sX union: phase1 sDw[0,800) sS[800,1600) sL2[1600,2000)
  //           epilogue sAcc[0,1024) sSig[1024,2112) sBn[2112,3152)
  __shared__ __align__(16) float sX[3152];
  __shared__ float sFeat[80];

  float* sDw = sX;
  float* sS = sX + 800;
  float* sL2 = sX + 1600;

  const int tid = threadIdx.x;
  const int posBase = blockIdx.x * 16;

  // ---- Phase 1a-1: windowed increments Dw[p][r][i] ----
  for (int u = tid; u < 800; u += 512) {
    int p = u / 50, rr = u - p * 50;
    int r = rr / 5, i = rr - r * 5;
    int pos = posBase + p;
    int t = pos & (TT - 1);
    int q = t + r - W;
    float dv = 0.f;
    if (q >= 0) {
      const float* fb = F + (size_t)(pos - t) * 5;
      dv = fb[(q + 1) * 5 + i] - fb[q * 5 + i];
    }
    sDw[u] = dv;
  }
  if (tid < 80) sFeat[tid] = F[(size_t)posBase * 5 + tid];
  __syncthreads();

  // ---- Phase 1a-2: reverse cumsum S; lvl1 -> phi[0..5) ----
  if (tid < 80) {
    int p = tid / 5, i = tid - (tid / 5) * 5;
    float s = 0.f;
#pragma unroll
    for (int r = W - 1; r >= 0; --r) {
      s += sDw[p * 50 + r * 5 + i];
      sS[p * 50 + r * 5 + i] = s;
    }
    unsigned short hi, lo;
    splitTrunc(s, hi, lo);
    phiH[p][i] = hi;
    phiL[p][i] = lo;
  }
  __syncthreads();

  // ---- Phase 1b: l2f -> phi[5..30) + sL2, l3f -> phi[30..155) ----
  if (tid < 400) {
    int p = tid / 25, ef = tid - (tid / 25) * 25;
    int e = ef / 5, fi = ef - e * 5;
    const float* dwp = sDw + p * 50;
    const float* sp = sS + p * 50;
    float a = 0.f;
    float l3a[5] = {0.f, 0.f, 0.f, 0.f, 0.f};
#pragma unroll
    for (int r = W - 1; r >= 0; --r) {
      float aa = a;
#pragma unroll
      for (int i = 0; i < 5; ++i) l3a[i] = fmaf(dwp[r * 5 + i], aa, l3a[i]);
      a = fmaf(dwp[r * 5 + e], sp[r * 5 + fi], a);
    }
    sL2[p * 25 + ef] = a;
    unsigned short hi, lo;
    splitTrunc(a, hi, lo);
    phiH[p][5 + ef] = hi;
    phiL[p][5 + ef] = lo;
#pragma unroll
    for (int i = 0; i < 5; ++i) {
      splitTrunc(l3a[i], hi, lo);
      phiH[p][30 + i * 25 + ef] = hi;
      phiL[p][30 + i * 25 + ef] = lo;
    }
  }
  // zero pads: phi[155..160) and phi[785..800) (disjoint from 1b's writes)
  if (tid < 320) {
    int p = tid / 20, mm = tid - (tid / 20) * 20;
    int kk = (mm < 5) ? (155 + mm) : (780 + mm);
    phiH[p][kk] = 0;
    phiL[p][kk] = 0;
  }
  __syncthreads();

  // ---- Phase 1c: l4f[a2] = l2[i]*l2[j] -> phi[160+a2), packed b32 writes ----
  {
    int p = tid >> 5, t32 = tid & 31;
    int base = t32 * 20;
    int count = (t32 == 31) ? 5 : 20;
    const float* l2p = sL2 + p * 25;
    int i = base / 25, j = base - i * 25;
    unsigned short* rowH = &phiH[p][160 + base];
    unsigned short* rowL = &phiL[p][160 + base];
    int mEnd = count & ~1;
    for (int m = 0; m < mEnd; m += 2) {
      float v0 = l2p[i] * l2p[j];
      j++; if (j == 25) { j = 0; i++; }
      float v1 = l2p[i] * l2p[j];
      j++; if (j == 25) { j = 0; i++; }
      unsigned short h0, lo0, h1, lo1;
      splitTrunc(v0, h0, lo0);
      splitTrunc(v1, h1, lo1);
      *(unsigned int*)(rowH + m) = (unsigned int)h0 | ((unsigned int)h1 << 16);
      *(unsigned int*)(rowL + m) = (unsigned int)lo0 | ((unsigned int)lo1 << 16);
    }
    if (count & 1) {
      float v0 = l2p[i] * l2p[j];
      unsigned short h0, lo0;
      splitTrunc(v0, h0, lo0);
      rowH[mEnd] = h0;
      rowL[mEnd] = lo0;
    }
  }
  __syncthreads();

  // ---- Phase 2: MFMA. wave = (h-tile ht, K-group kg) ----
  const int lane = tid & 63;
  const int wvAll = tid >> 6;  // 0..7
  const int ht = wvAll & 3, kg = wvAll >> 2;
  const int col = lane & 15, quad = lane >> 4;
  const int hw = ht * 16;
  const int arow = hw + col;

  const unsigned short* bHp = &phiH[col][quad * 8];
  const unsigned short* bLp = &phiL[col][quad * 8];
  const unsigned short* a4H = WtH + 14336 + arow * 800 + quad * 8;
  const unsigned short* a4L = WtL + 14336 + arow * 800 + quad * 8;

  f32x4 acc4a = {0.f, 0.f, 0.f, 0.f}, acc4b = {0.f, 0.f, 0.f, 0.f};
  f32x4 acc3a = {0.f, 0.f, 0.f, 0.f}, acc3b = {0.f, 0.f, 0.f, 0.f};
  f32x4 acc2 = {0.f, 0.f, 0.f, 0.f}, acc1 = {0.f, 0.f, 0.f, 0.f};

  if (kg == 0) {  // L4 s in [0,16): 48 MFMAs
    for (int s = 0; s < 16; ++s) {
      bf16x8 bh = *(const bf16x8*)(bHp + s * 32);
      bf16x8 bl = *(const bf16x8*)(bLp + s * 32);
      bf16x8 ah = *(const bf16x8*)(a4H + s * 32);
      bf16x8 al = *(const bf16x8*)(a4L + s * 32);
      acc4a = MFMA16(ah, bh, acc4a);
      acc4b = MFMA16(ah, bl, acc4b);
      acc4b = MFMA16(al, bh, acc4b);
    }
  } else {  // L4 s in [16,25) + L3 + L2 + L1: 48 MFMAs
    for (int s = 16; s < 25; ++s) {
      bf16x8 bh = *(const bf16x8*)(bHp + s * 32);
      bf16x8 bl = *(const bf16x8*)(bLp + s * 32);
      bf16x8 ah = *(const bf16x8*)(a4H + s * 32);
      bf16x8 al = *(const bf16x8*)(a4L + s * 32);
      acc4a = MFMA16(ah, bh, acc4a);
      acc4b = MFMA16(ah, bl, acc4b);
      acc4b = MFMA16(al, bh, acc4b);
    }
    const unsigned short* a3H = WtH + 4096 + arow * 160 + quad * 8;
    const unsigned short* a3L = WtL + 4096 + arow * 160 + quad * 8;
    for (int s = 0; s < 5; ++s) {
      bf16x8 bh = *(const bf16x8*)(bHp + s * 32);
      bf16x8 bl = *(const bf16x8*)(bLp + s * 32);
      bf16x8 ch = *(const bf16x8*)(a3H + s * 32);
      bf16x8 cl = *(const bf16x8*)(a3L + s * 32);
      acc3a = MFMA16(ch, bh, acc3a);
      acc3b = MFMA16(ch, bl, acc3b);
      acc3b = MFMA16(cl, bh, acc3b);
    }
    bf16x8 bh0 = *(const bf16x8*)(bHp);
    bf16x8 bl0 = *(const bf16x8*)(bLp);
    const unsigned short* a2H = WtH + 2048 + arow * 32 + quad * 8;
    const unsigned short* a2L = WtL + 2048 + arow * 32 + quad * 8;
    bf16x8 dh = *(const bf16x8*)a2H;
    bf16x8 dl = *(const bf16x8*)a2L;
    acc2 = MFMA16(dh, bh0, acc2);
    acc2 = MFMA16(dh, bl0, acc2);
    acc2 = MFMA16(dl, bh0, acc2);
    const unsigned short* a1H = WtH + arow * 32 + quad * 8;
    const unsigned short* a1L = WtL + arow * 32 + quad * 8;
    bf16x8 eh = *(const bf16x8*)a1H;
    bf16x8 el = *(const bf16x8*)a1L;
    acc1 = MFMA16(eh, bh0, acc1);
    acc1 = MFMA16(eh, bl0, acc1);
    acc1 = MFMA16(el, bh0, acc1);
  }

  // ---- gate-combine partials; reduce K-groups via LDS ----
  const int pos = posBase + col;
  const int t = pos & (TT - 1);
  float4 g = ((const float4*)gate)[pos];
  const float g0 = g.x;
  const float g1 = (t >= 1) ? g.y : 0.f;
  const float g2 = (t >= 2) ? g.z : 0.f;
  const float g3 = (t >= 3) ? g.w : 0.f;

  if (kg == 1) {
    f32x4 a4 = acc4a + acc4b;
    f32x4 a3 = acc3a + acc3b;
    f32x4 v;
#pragma unroll
    for (int r = 0; r < 4; ++r)
      v[r] = g0 * acc1[r] + g1 * acc2[r] + g2 * a3[r] + g3 * a4[r];
    *(f32x4*)&sX[(ht * 64 + lane) * 4] = v;
  }
  __syncthreads();
  if (kg == 0) {
    f32x4 a4 = acc4a + acc4b;
    f32x4 vo = *(const f32x4*)&sX[(ht * 64 + lane) * 4];
    float* sSig = sX + 1024;  // [16][68]
#pragma unroll
    for (int r = 0; r < 4; ++r) {
      int h = hw + quad * 4 + r;
      float bias = g0 * p1b[h] + g1 * p2b[h] + g2 * p3b[h] + g3 * p4b[h];
      sSig[col * 68 + h] = vo[r] + g3 * a4[r] + bias;
    }
  }
  __syncthreads();

  // ---- Head: h1+BN. wave handles 2 positions, lane = output channel j ----
  {
    const float* sSig = sX + 1024;
    float* sBn = sX + 2112;  // [16][65]
    const int j = lane;
    const int pA = wvAll * 2, pB = pA + 1;
    float a0 = b1[j], a1 = a0;
    const float* sg0 = sSig + pA * 68;
    const float* sg1 = sSig + pB * 68;
    for (int i = 0; i < 64; ++i) {
      float wt = w1[i * 64 + j];
      a0 = fmaf(sg0[i], wt, a0);
      a1 = fmaf(sg1[i], wt, a1);
    }
#pragma unroll
    for (int i = 0; i < 5; ++i) {
      float wt = w1[(64 + i) * 64 + j];
      a0 = fmaf(sFeat[pA * 5 + i], wt, a0);
      a1 = fmaf(sFeat[pB * 5 + i], wt, a1);
    }
    float sc = gam[j] * rsqrtf(rvar[j] + 1e-5f);
    float rm = rmean[j], be = bet[j];
    sBn[pA * 65 + j] = fmaf(fmaxf(a0, 0.f) - rm, sc, be);
    sBn[pB * 65 + j] = fmaf(fmaxf(a1, 0.f) - rm, sc, be);
  }
  __syncthreads();

  // ---- h2 + output: 512 tasks = 16 pos x 32 k ----
  {
    const float* sBn = sX + 2112;
    const float b3s = b3[0];
    int p = tid >> 5, k = tid & 31;
    const float* bnp = sBn + p * 65;
    float a = b2[k];
    for (int jj = 0; jj < 64; ++jj) a = fmaf(bnp[jj], w2[jj * 32 + k], a);
    float partial = fmaxf(a, 0.f) * w3[k];
#pragma unroll
    for (int off = 16; off >= 1; off >>= 1) partial += __shfl_xor(partial, off, 32);
    if (k == 0) out[posBase + p] = 1.5f * tanhf(partial + b3s);
  }
}

extern "C" void kernel_launch(void* const* d_in, const int* in_sizes, int n_in,
                              void* d_out, int out_size, void* d_ws, size_t ws_size,
                              hipStream_t stream) {
  const float* F = (const float*)d_in[0];
  const float* hw1 = (const float*)d_in[1];
  const float* hb1 = (const float*)d_in[2];
  const float* hw2 = (const float*)d_in[3];
  const float* hb2 = (const float*)d_in[4];
  const float* hw3 = (const float*)d_in[5];
  const float* hb3 = (const float*)d_in[6];
  const float* gw1 = (const float*)d_in[7];
  const float* gb1 = (const float*)d_in[8];
  const float* gw2 = (const float*)d_in[9];
  const float* gb2 = (const float*)d_in[10];
  const float* p1 = (const float*)d_in[11];
  const float* p1b = (const float*)d_in[12];
  const float* p2 = (const float*)d_in[13];
  const float* p2b = (const float*)d_in[14];
  const float* p3 = (const float*)d_in[15];
  const float* p3b = (const float*)d_in[16];
  const float* p4 = (const float*)d_in[17];
  const float* p4b = (const float*)d_in[18];
  const float* w1 = (const float*)d_in[19];
  const float* b1 = (const float*)d_in[20];
  const float* gam = (const float*)d_in[21];
  const float* bet = (const float*)d_in[22];
  const float* rmean = (const float*)d_in[23];
  const float* rvar = (const float*)d_in[24];
  const float* w2 = (const float*)d_in[25];
  const float* b2 = (const float*)d_in[26];
  const float* w3 = (const float*)d_in[27];
  const float* b3 = (const float*)d_in[28];

  float* ws = (float*)d_ws;
  float* gate = ws;                                      // 262144 floats
  unsigned short* WtH = (unsigned short*)(ws + 262144);  // 65536 ushorts
  unsigned short* WtL = WtH + 65536;                     // 65536 ushorts
  float* out = (float*)d_out;                            // 65536 floats

  pre_kernel<<<512, 256, 0, stream>>>(F, hw1, hb1, hw2, hb2, hw3, hb3, gw1,
                                      gb1, gw2, gb2, p1, p2, p3, p4, WtH, WtL,
                                      gate);
  sig_kernel<<<4096, 512, 0, stream>>>(F, gate, WtH, WtL, p1b, p2b, p3b, p4b,
                                       w1, b1, gam, bet, rmean, rvar, w2, b2,
                                       w3, b3, out);
}